// Round 10
// baseline (471.807 us; speedup 1.0000x reference)
//
#include <hip/hip_runtime.h>

#define EPSB 1e-5f
#define NEG 0.2f

__device__ __forceinline__ float lrelu(float y) { return y >= 0.f ? y : NEG * y; }

// async global->LDS 16B/lane (wave-uniform LDS dest, per-lane global src)
typedef const __attribute__((address_space(1))) unsigned int gas1_u32;
typedef __attribute__((address_space(3))) unsigned int as3_u32;
__device__ __forceinline__ void gload16(const float* g, float* l) {
  __builtin_amdgcn_global_load_lds((gas1_u32*)g, (as3_u32*)l, 16, 0, 0);
}
#define WAITVM(N) asm volatile("s_waitcnt vmcnt(" #N ")" ::: "memory")

// barrier that does NOT drain vmcnt (keeps global prefetches in flight);
// lgkmcnt(0) gives LDS store/load visibility, s_barrier syncs the block.
__device__ __forceinline__ void barrier_nodrain() {
  asm volatile("s_waitcnt lgkmcnt(0)" ::: "memory");
  __builtin_amdgcn_s_barrier();
  __builtin_amdgcn_sched_barrier(0);
}

// ---------------------------------------------------------------------------
// Fused conv frontend (unchanged, validated): output xt[p][b][s].
// ---------------------------------------------------------------------------
__global__ __launch_bounds__(256) void k_front(
    const float* __restrict__ data, const float* __restrict__ w1,
    const float* __restrict__ w2, const float* __restrict__ w3,
    const float* __restrict__ lw, const float* __restrict__ bg,
    const float* __restrict__ bb, const float* __restrict__ bm,
    const float* __restrict__ bv, float* __restrict__ xt)
{
  __shared__ float x1s[32][132];
  __shared__ float x2s[32][40];
  __shared__ float x3s[32][20];
  const int b = blockIdx.x >> 3, q = blockIdx.x & 7, t = threadIdx.x;
  const int o1s = (937*q)/8, o1e = (937*(q+1))/8;
  const int o2s = (234*q)/8, o2e = (234*(q+1))/8;
  const int o3s = (116*q)/8, o3e = (116*(q+1))/8;
  int n2s = min(o2s, 2*o3s);
  int n2e = max(o2e, 2*(o3e-1)+4); if (n2e > 234) n2e = 234;
  int n1s = min(o1s, 4*n2s);
  int n1e = max(o1e, 4*(n2e-1)+5); if (n1e > 937) n1e = 937;
  const int w1w = n1e - n1s, w2w = n2e - n2s, w3w = o3e - o3s;

  for (int idx = t; idx < 32*w1w; idx += 256) {
    int c = idx / w1w, j = n1s + idx % w1w;
    float acc = 0.f;
    int base = 5*j - 2;
    #pragma unroll
    for (int k = 0; k < 5; ++k) {
      int pos = base + k;
      float d = (pos >= 0 && pos < 4681) ? data[b*4681 + pos] : 0.f;
      acc += w1[c*5 + k] * d;
    }
    float sc = bg[c] * rsqrtf(bv[c] + EPSB);
    x1s[c][j - n1s] = lrelu((acc - bm[c]) * sc + bb[c]);
  }
  __syncthreads();
  for (int idx = t; idx < 32*w2w; idx += 256) {
    int c = idx / w2w, j = n2s + idx % w2w;
    float acc = 0.f;
    int col = 4*j - n1s;
    for (int ci = 0; ci < 32; ++ci) {
      #pragma unroll
      for (int k = 0; k < 5; ++k) acc += w2[(c*32 + ci)*5 + k] * x1s[ci][col + k];
    }
    float sc = bg[32+c] * rsqrtf(bv[32+c] + EPSB);
    x2s[c][j - n2s] = lrelu((acc - bm[32+c]) * sc + bb[32+c]);
  }
  __syncthreads();
  for (int idx = t; idx < 32*w3w; idx += 256) {
    int c = idx / w3w, j = o3s + idx % w3w;
    float acc = 0.f;
    int col = 2*j - n2s;
    for (int ci = 0; ci < 32; ++ci) {
      #pragma unroll
      for (int k = 0; k < 4; ++k) acc += w3[(c*32 + ci)*4 + k] * x2s[ci][col + k];
    }
    float sc = bg[64+c] * rsqrtf(bv[64+c] + EPSB);
    x3s[c][j - o3s] = lrelu((acc - bm[64+c]) * sc + bb[64+c]);
  }
  __syncthreads();
  const int np1 = o1e - o1s, np2 = o2e - o2s, np3 = o3e - o3s;
  const int np = np1 + np2 + np3;
  for (int idx = t; idx < np*32; idx += 256) {
    int pi = idx >> 5, s = idx & 31;
    float acc = 0.f;
    int p;
    if (pi < np1) {
      int j = o1s + pi; p = j;
      int col = j - n1s;
      for (int ci = 0; ci < 32; ++ci) acc += lw[s*32 + ci] * x1s[ci][col];
    } else if (pi < np1 + np2) {
      int j = o2s + (pi - np1); p = 937 + j;
      int col = j - n2s;
      for (int ci = 0; ci < 32; ++ci) acc += lw[s*32 + ci] * x2s[ci][col];
    } else {
      int j = o3s + (pi - np1 - np2); p = 1171 + j;
      int col = j - o3s;
      for (int ci = 0; ci < 32; ++ci) acc += lw[s*32 + ci] * x3s[ci][col];
    }
    float sc = bg[96+s] * rsqrtf(bv[96+s] + EPSB);
    xt[p*1024 + b*32 + s] = lrelu((acc - bm[96+s]) * sc + bb[96+s]);
  }
}

// ---------------------------------------------------------------------------
// Pass A v5: R4 structure EXACTLY (256 thr, same LDS/layouts, u stride 1287)
// with CORRECT counted vmcnt schedule (the only change vs R7):
//   __syncthreads drains the prologue; from there the in-order VM queue is
//   pp=0: [D1]            -> need D0 (drained)     WAIT(5)  (no-op, safe)
//   pp=1: [D2,S0]         -> need D1 (drained)     WAIT(10) (no-op, safe)
//   pp>=2: [D(p),S(p-2),D(p+1),S(p-1)] -> need D(p): 15 ops after it -> WAIT(15)
//   pp=7 (no D issued at pp=6): [D(p7),S5,S6]      -> WAIT(10)
// Prefetch is unconditional for pp<6 with clamped source so the queue shape
// is uniform for the 7-p last chunk (its final iter pp=6 then has exactly
// [D(1286),S4,Dclamp,S5] -> WAIT(15) correct).
// ---------------------------------------------------------------------------
__global__ __launch_bounds__(256) void k_uhat(
    const float* __restrict__ W, const float* __restrict__ xt,
    float* __restrict__ u, float* __restrict__ s0part)
{
  extern __shared__ float lds[];
  float* xs = lds;                       // [8 p][32 b][32 s] swizzled
  float* wbuf = lds + 8192;              // [4 waves][2][1280]
  const int t = threadIdx.x;
  const int wi = blockIdx.x*4 + (t >> 6);
  const int lane = t & 63;
  const int l = wi % 40, chunk = wi / 40;
  const int vg = lane >> 3, bg = lane & 7;
  const int p0 = chunk * 8;
  float* myw = wbuf + (t >> 6) * 2560;
  const float* Wl = W + (size_t)l * 1287 * 1280;

  for (int g = t; g < 2048; g += 256) {
    int pl = g >> 8, rem = g & 255;
    int b = rem >> 3, s4 = rem & 7;
    int pg = p0 + pl;
    float4 v = make_float4(0.f, 0.f, 0.f, 0.f);
    if (pg < 1287) v = *(const float4*)(xt + pg*1024 + b*32 + s4*4);
    *(float4*)(xs + pl*1024 + b*32 + ((s4 ^ (b >> 2)) << 2)) = v;
  }
  // prologue DMA: D(p0)->buf0, D(p0+1)->buf1 (p0+1 <= 1281 < 1287 always)
  #pragma unroll
  for (int i = 0; i < 5; ++i) {
    int g = i*64 + lane, v = g >> 3, s4 = (g & 7) ^ (v & 7);
    gload16(Wl + (size_t)p0*1280 + (v*8 + s4)*4, myw + i*256);
  }
  #pragma unroll
  for (int i = 0; i < 5; ++i) {
    int g = i*64 + lane, v = g >> 3, s4 = (g & 7) ^ (v & 7);
    gload16(Wl + (size_t)(p0+1)*1280 + (v*8 + s4)*4, myw + 1280 + i*256);
  }
  __syncthreads();   // drains prologue (vmcnt 0) -- accounted for above

  float s0acc[5][4] = {};

  auto body = [&](int pp, bool pf) {
    const int p = p0 + pp;
    const int cur = pp & 1;
    const float* wb = myw + cur*1280;
    const float* xp = xs + pp*1024;
    float acc[5][4] = {};
    #pragma unroll
    for (int s4 = 0; s4 < 8; ++s4) {
      float4 wv[5], xv[4];
      #pragma unroll
      for (int i = 0; i < 5; ++i) {
        int v = vg*5 + i;
        wv[i] = *(const float4*)(wb + v*32 + ((s4 ^ (v & 7)) << 2));
      }
      #pragma unroll
      for (int j = 0; j < 4; ++j) {
        int b = bg*4 + j;
        xv[j] = *(const float4*)(xp + b*32 + ((s4 ^ (b >> 2)) << 2));
      }
      #pragma unroll
      for (int i = 0; i < 5; ++i)
        #pragma unroll
        for (int j = 0; j < 4; ++j)
          acc[i][j] += wv[i].x*xv[j].x + wv[i].y*xv[j].y + wv[i].z*xv[j].z + wv[i].w*xv[j].w;
    }
    if (pf) {
      // all ds_reads of this buffer must land before DMA overwrites it
      asm volatile("s_waitcnt lgkmcnt(0)" ::: "memory");
      __builtin_amdgcn_sched_barrier(0);
      int psrc = p + 2; if (psrc > 1286) psrc = 1286;  // clamp: pad-only data
      #pragma unroll
      for (int i = 0; i < 5; ++i) {
        int g = i*64 + lane, v = g >> 3, s4 = (g & 7) ^ (v & 7);
        gload16(Wl + (size_t)psrc*1280 + (v*8 + s4)*4, myw + cur*1280 + i*256);
      }
    }
    float* up = u + ((size_t)(bg*1287 + p))*6400 + l*160;
    #pragma unroll
    for (int i = 0; i < 5; ++i) {
      int v = vg*5 + i;
      *(float4*)(up + v*4) = make_float4(acc[i][0], acc[i][1], acc[i][2], acc[i][3]);
      #pragma unroll
      for (int j = 0; j < 4; ++j) s0acc[i][j] += acc[i][j];
    }
  };

  WAITVM(5);  body(0, true);
  WAITVM(10); body(1, true);
  #pragma unroll 1
  for (int pp = 2; pp <= 6; ++pp) {   // all chunks have >= 7 valid p's
    WAITVM(15);
    body(pp, pp < 6);
  }
  if (p0 + 7 < 1287) {                // full chunks only
    WAITVM(10);
    body(7, false);
  }

  float* sp = s0part + (size_t)chunk*51200 + l*1280;
  #pragma unroll
  for (int i = 0; i < 5; ++i) {
    int v = vg*5 + i;
    *(float4*)(sp + v*32 + bg*4) =
        make_float4(s0acc[i][0], s0acc[i][1], s0acc[i][2], s0acc[i][3]);
  }
}

// ---------------------------------------------------------------------------
// squash kernels (unchanged, validated)
// ---------------------------------------------------------------------------
__global__ __launch_bounds__(64) void k_squash0(
    const float* __restrict__ s0, float* __restrict__ v0t)
{
  const int b = blockIdx.x / 40, l = blockIdx.x % 40, t = threadIdx.x;
  float s = 0.f;
  if (t < 40) s = s0[(l*40 + t)*32 + b] * (1.f/40.f);
  float sq = s*s;
  #pragma unroll
  for (int d = 1; d < 64; d <<= 1) sq += __shfl_xor(sq, d);
  float scale = sq > 0.f ? sq / ((1.f + sq) * sqrtf(sq)) : 0.f;
  if (t < 40) v0t[((size_t)(b >> 2)*1600 + l*40 + t)*4 + (b & 3)] = s * scale;
}

__global__ __launch_bounds__(64) void k_squash1(
    const float* __restrict__ sred, float* __restrict__ v1t)
{
  const int b = blockIdx.x / 40, l = blockIdx.x % 40, t = threadIdx.x;
  float s = 0.f;
  size_t off = ((size_t)(b >> 2)*1600 + l*40 + t)*4 + (b & 3);
  if (t < 40) s = sred[off];
  float sq = s*s;
  #pragma unroll
  for (int d = 1; d < 64; d <<= 1) sq += __shfl_xor(sq, d);
  float scale = sq > 0.f ? sq / ((1.f + sq) * sqrtf(sq)) : 0.f;
  if (t < 40) v1t[off] = s * scale;
}

__global__ __launch_bounds__(64) void k_final(
    const float* __restrict__ sred, float* __restrict__ out)
{
  const int b = blockIdx.x / 40, l = blockIdx.x % 40, t = threadIdx.x;
  float s = 0.f;
  if (t < 40) s = sred[((size_t)(b >> 2)*1600 + l*40 + t)*4 + (b & 3)];
  float sq = s*s, ss = s;
  #pragma unroll
  for (int d = 1; d < 64; d <<= 1) { sq += __shfl_xor(sq, d); ss += __shfl_xor(ss, d); }
  float scale = sq > 0.f ? sq / ((1.f + sq) * sqrtf(sq)) : 0.f;
  if (t == 0) out[b*40 + l] = ss * scale;
}

// ---------------------------------------------------------------------------
// k_route4 (unchanged from R9, validated absmax 0.0)
// ---------------------------------------------------------------------------
#define RPC 13
#define NCHUNK 99               // 99*13 = 1287 exactly
__global__ __launch_bounds__(400) void k_route4(
    const float* __restrict__ u, const float* __restrict__ vprev,
    float* __restrict__ b1g, float* __restrict__ spart, int pass)
{
  __shared__ float4 dred[400];
  __shared__ float dot_lds[160];   // [b4][40]
  __shared__ float c_lds[160];     // [b4][40]
  const int q4 = blockIdx.x & 7, chunk = blockIdx.x >> 3;
  const int t = threadIdx.x;            // t = l*10 + vq
  const int l = t / 10;
  const int p0 = chunk * RPC;
  const float4* u4 = (const float4*)u;
  const float4* vp4 = (const float4*)vprev + (size_t)q4*1600;

  float4 vv[4], s4[4], uu[2][4];
  float bprev[2] = {0.f, 0.f};
  #pragma unroll
  for (int j = 0; j < 4; ++j) {
    vv[j] = vp4[t*4 + j];
    s4[j] = make_float4(0.f, 0.f, 0.f, 0.f);
  }
  {
    const float4* up = u4 + ((size_t)q4*1287 + p0)*1600;
    #pragma unroll
    for (int j = 0; j < 4; ++j) uu[0][j] = up[t*4 + j];
    if (pass == 2 && t < 160) bprev[0] = b1g[((size_t)q4*1287 + p0)*160 + t];
  }

  #pragma unroll 2
  for (int pl = 0; pl < RPC; ++pl) {
    const int cur = pl & 1, nxt = cur ^ 1;
    const size_t qp = (size_t)q4*1287 + p0 + pl;
    float4 dp = make_float4(0.f, 0.f, 0.f, 0.f);
    #pragma unroll
    for (int j = 0; j < 4; ++j) {
      dp.x += uu[cur][j].x*vv[j].x; dp.y += uu[cur][j].y*vv[j].y;
      dp.z += uu[cur][j].z*vv[j].z; dp.w += uu[cur][j].w*vv[j].w;
    }
    dred[t] = dp;
    if (pl < RPC-1) {
      const float4* upn = u4 + (qp + 1)*1600;
      #pragma unroll
      for (int j = 0; j < 4; ++j) uu[nxt][j] = upn[t*4 + j];
      if (pass == 2 && t < 160) bprev[nxt] = b1g[(qp + 1)*160 + t];
    }
    barrier_nodrain();
    if (t < 160) {
      const int lr = t >> 2, b4 = t & 3;
      float d = 0.f;
      #pragma unroll
      for (int vq = 0; vq < 10; ++vq)
        d += ((const float*)&dred[lr*10 + vq])[b4];
      if (pass == 2) d += bprev[cur];
      else           b1g[qp*160 + t] = d;
      dot_lds[b4*40 + lr] = d;
    }
    barrier_nodrain();
    if (t < 256) {
      const int b4 = t >> 6, ll = t & 63;
      float d = (ll < 40) ? dot_lds[b4*40 + ll] : -1e30f;
      float m = d;
      #pragma unroll
      for (int off = 32; off; off >>= 1) m = fmaxf(m, __shfl_xor(m, off));
      float e = expf(d - m);
      float Z = e;
      #pragma unroll
      for (int off = 32; off; off >>= 1) Z += __shfl_xor(Z, off);
      if (ll < 40) c_lds[b4*40 + ll] = e * (1.f / Z);
    }
    barrier_nodrain();
    {
      float c0 = c_lds[l], c1 = c_lds[40 + l], c2 = c_lds[80 + l], c3 = c_lds[120 + l];
      #pragma unroll
      for (int j = 0; j < 4; ++j) {
        s4[j].x += uu[cur][j].x*c0; s4[j].y += uu[cur][j].y*c1;
        s4[j].z += uu[cur][j].z*c2; s4[j].w += uu[cur][j].w*c3;
      }
    }
  }
  float4* sp = (float4*)(spart + ((size_t)chunk*8 + q4)*6400);
  #pragma unroll
  for (int j = 0; j < 4; ++j) sp[t*4 + j] = s4[j];
}

// sout[w] = sum_{c<n} src[c][w], w < 51200
__global__ __launch_bounds__(256) void k_reduceN(
    const float* __restrict__ src, float* __restrict__ sout, int n)
{
  const int w = blockIdx.x*256 + threadIdx.x;
  float s = 0.f;
  #pragma unroll 4
  for (int c = 0; c < n; ++c) s += src[(size_t)c*51200 + w];
  sout[w] = s;
}

// ---------------------------------------------------------------------------
extern "C" void kernel_launch(void* const* d_in, const int* in_sizes, int n_in,
                              void* d_out, int out_size, void* d_ws, size_t ws_size,
                              hipStream_t stream)
{
  const float* data = (const float*)d_in[0];
  const float* w1   = (const float*)d_in[1];
  const float* w2   = (const float*)d_in[2];
  const float* w3   = (const float*)d_in[3];
  const float* lw   = (const float*)d_in[4];
  const float* bg   = (const float*)d_in[5];
  const float* bb   = (const float*)d_in[6];
  const float* bm   = (const float*)d_in[7];
  const float* bv   = (const float*)d_in[8];
  const float* W    = (const float*)d_in[9];
  float* out = (float*)d_out;

  float* u      = (float*)d_ws;            // 8*1287*6400 = 65,894,400
  float* s0     = u + 65894400;            // 51,200
  float* v0t    = s0 + 51200;              // 51,200
  float* v1t    = v0t + 51200;             // 51,200
  float* s1     = v1t + 51200;             // 51,200
  float* xt     = s1 + 51200;              // 1,317,888
  float* big    = xt + 1317888;
  float* s0part = big;                     // [161][51200] (dead after reduce)
  float* b1g    = big;                     // 1,647,360 (live pass1 -> pass2)
  float* spart  = b1g + 1647360;           // [99][51200] = 5,068,800
  // total ~303 MB

  const int KU_LDS = (8192 + 4*2*1280) * 4;  // 73,728 B
  hipFuncSetAttribute((const void*)k_uhat,
                      hipFuncAttributeMaxDynamicSharedMemorySize, KU_LDS);

  k_front<<<256, 256, 0, stream>>>(data, w1, w2, w3, lw, bg, bb, bm, bv, xt);
  k_uhat<<<1610, 256, KU_LDS, stream>>>(W, xt, u, s0part);
  k_reduceN<<<200, 256, 0, stream>>>(s0part, s0, 161);
  k_squash0<<<1280, 64, 0, stream>>>(s0, v0t);

  k_route4<<<NCHUNK*8, 400, 0, stream>>>(u, v0t, b1g, spart, 1);
  k_reduceN<<<200, 256, 0, stream>>>(spart, s1, NCHUNK);
  k_squash1<<<1280, 64, 0, stream>>>(s1, v1t);

  k_route4<<<NCHUNK*8, 400, 0, stream>>>(u, v1t, b1g, spart, 2);
  k_reduceN<<<200, 256, 0, stream>>>(spart, s0, NCHUNK);
  k_final<<<1280, 64, 0, stream>>>(s0, out);
}

// Round 11
// 454.256 us; speedup vs baseline: 1.0386x; 1.0386x over previous
//
#include <hip/hip_runtime.h>

#define EPSB 1e-5f
#define NEG 0.2f

__device__ __forceinline__ float lrelu(float y) { return y >= 0.f ? y : NEG * y; }

// async global->LDS 16B/lane (wave-uniform LDS dest, per-lane global src)
typedef const __attribute__((address_space(1))) unsigned int gas1_u32;
typedef __attribute__((address_space(3))) unsigned int as3_u32;
__device__ __forceinline__ void gload16(const float* g, float* l) {
  __builtin_amdgcn_global_load_lds((gas1_u32*)g, (as3_u32*)l, 16, 0, 0);
}
#define WAITVM(N) asm volatile("s_waitcnt vmcnt(" #N ")" ::: "memory")

// barrier that does NOT drain vmcnt (keeps global prefetches in flight);
// lgkmcnt(0) gives LDS store/load visibility, s_barrier syncs the block.
__device__ __forceinline__ void barrier_nodrain() {
  asm volatile("s_waitcnt lgkmcnt(0)" ::: "memory");
  __builtin_amdgcn_s_barrier();
  __builtin_amdgcn_sched_barrier(0);
}

// ---------------------------------------------------------------------------
// Fused conv frontend (unchanged, validated): output xt[p][b][s].
// ---------------------------------------------------------------------------
__global__ __launch_bounds__(256) void k_front(
    const float* __restrict__ data, const float* __restrict__ w1,
    const float* __restrict__ w2, const float* __restrict__ w3,
    const float* __restrict__ lw, const float* __restrict__ bg,
    const float* __restrict__ bb, const float* __restrict__ bm,
    const float* __restrict__ bv, float* __restrict__ xt)
{
  __shared__ float x1s[32][132];
  __shared__ float x2s[32][40];
  __shared__ float x3s[32][20];
  const int b = blockIdx.x >> 3, q = blockIdx.x & 7, t = threadIdx.x;
  const int o1s = (937*q)/8, o1e = (937*(q+1))/8;
  const int o2s = (234*q)/8, o2e = (234*(q+1))/8;
  const int o3s = (116*q)/8, o3e = (116*(q+1))/8;
  int n2s = min(o2s, 2*o3s);
  int n2e = max(o2e, 2*(o3e-1)+4); if (n2e > 234) n2e = 234;
  int n1s = min(o1s, 4*n2s);
  int n1e = max(o1e, 4*(n2e-1)+5); if (n1e > 937) n1e = 937;
  const int w1w = n1e - n1s, w2w = n2e - n2s, w3w = o3e - o3s;

  for (int idx = t; idx < 32*w1w; idx += 256) {
    int c = idx / w1w, j = n1s + idx % w1w;
    float acc = 0.f;
    int base = 5*j - 2;
    #pragma unroll
    for (int k = 0; k < 5; ++k) {
      int pos = base + k;
      float d = (pos >= 0 && pos < 4681) ? data[b*4681 + pos] : 0.f;
      acc += w1[c*5 + k] * d;
    }
    float sc = bg[c] * rsqrtf(bv[c] + EPSB);
    x1s[c][j - n1s] = lrelu((acc - bm[c]) * sc + bb[c]);
  }
  __syncthreads();
  for (int idx = t; idx < 32*w2w; idx += 256) {
    int c = idx / w2w, j = n2s + idx % w2w;
    float acc = 0.f;
    int col = 4*j - n1s;
    for (int ci = 0; ci < 32; ++ci) {
      #pragma unroll
      for (int k = 0; k < 5; ++k) acc += w2[(c*32 + ci)*5 + k] * x1s[ci][col + k];
    }
    float sc = bg[32+c] * rsqrtf(bv[32+c] + EPSB);
    x2s[c][j - n2s] = lrelu((acc - bm[32+c]) * sc + bb[32+c]);
  }
  __syncthreads();
  for (int idx = t; idx < 32*w3w; idx += 256) {
    int c = idx / w3w, j = o3s + idx % w3w;
    float acc = 0.f;
    int col = 2*j - n2s;
    for (int ci = 0; ci < 32; ++ci) {
      #pragma unroll
      for (int k = 0; k < 4; ++k) acc += w3[(c*32 + ci)*4 + k] * x2s[ci][col + k];
    }
    float sc = bg[64+c] * rsqrtf(bv[64+c] + EPSB);
    x3s[c][j - o3s] = lrelu((acc - bm[64+c]) * sc + bb[64+c]);
  }
  __syncthreads();
  const int np1 = o1e - o1s, np2 = o2e - o2s, np3 = o3e - o3s;
  const int np = np1 + np2 + np3;
  for (int idx = t; idx < np*32; idx += 256) {
    int pi = idx >> 5, s = idx & 31;
    float acc = 0.f;
    int p;
    if (pi < np1) {
      int j = o1s + pi; p = j;
      int col = j - n1s;
      for (int ci = 0; ci < 32; ++ci) acc += lw[s*32 + ci] * x1s[ci][col];
    } else if (pi < np1 + np2) {
      int j = o2s + (pi - np1); p = 937 + j;
      int col = j - n2s;
      for (int ci = 0; ci < 32; ++ci) acc += lw[s*32 + ci] * x2s[ci][col];
    } else {
      int j = o3s + (pi - np1 - np2); p = 1171 + j;
      int col = j - o3s;
      for (int ci = 0; ci < 32; ++ci) acc += lw[s*32 + ci] * x3s[ci][col];
    }
    float sc = bg[96+s] * rsqrtf(bv[96+s] + EPSB);
    xt[p*1024 + b*32 + s] = lrelu((acc - bm[96+s]) * sc + bb[96+s]);
  }
}

// ---------------------------------------------------------------------------
// Pass A: EXACT R4 version (best measured: 193 us, 3x reproduced). Do not
// touch: R5/R6/R10 schedule/shape variants all regressed.
// ---------------------------------------------------------------------------
__global__ __launch_bounds__(256) void k_uhat(
    const float* __restrict__ W, const float* __restrict__ xt,
    float* __restrict__ u, float* __restrict__ s0part)
{
  extern __shared__ float lds[];
  float* xs = lds;                       // [8 p][32 b][32 s] swizzled
  float* wbuf = lds + 8192;              // [4 waves][2][1280]
  const int t = threadIdx.x;
  const int wi = blockIdx.x*4 + (t >> 6);
  const int lane = t & 63;
  const int l = wi % 40, chunk = wi / 40;
  const int vg = lane >> 3, bg = lane & 7;
  const int p0 = chunk * 8;
  float* myw = wbuf + (t >> 6) * 2560;
  const float* Wl = W + (size_t)l * 1287 * 1280;

  for (int g = t; g < 2048; g += 256) {
    int pl = g >> 8, rem = g & 255;
    int b = rem >> 3, s4 = rem & 7;
    int pg = p0 + pl;
    float4 v = make_float4(0.f, 0.f, 0.f, 0.f);
    if (pg < 1287) v = *(const float4*)(xt + pg*1024 + b*32 + s4*4);
    *(float4*)(xs + pl*1024 + b*32 + ((s4 ^ (b >> 2)) << 2)) = v;
  }
  {
    #pragma unroll
    for (int i = 0; i < 5; ++i) {
      int g = i*64 + lane, v = g >> 3, s4 = (g & 7) ^ (v & 7);
      gload16(Wl + (size_t)p0*1280 + (v*8 + s4)*4, myw + i*256);
    }
    if (p0 + 1 < 1287) {
      #pragma unroll
      for (int i = 0; i < 5; ++i) {
        int g = i*64 + lane, v = g >> 3, s4 = (g & 7) ^ (v & 7);
        gload16(Wl + (size_t)(p0+1)*1280 + (v*8 + s4)*4, myw + 1280 + i*256);
      }
    }
  }
  __syncthreads();

  float s0acc[5][4] = {};
  int cur = 0;
  for (int pp = 0; pp < 8; ++pp) {
    int p = p0 + pp;
    if (p >= 1287) break;
    asm volatile("s_waitcnt lgkmcnt(0)" ::: "memory");
    WAITVM(5);
    const float* wb = myw + cur*1280;
    const float* xp = xs + pp*1024;
    float acc[5][4] = {};
    #pragma unroll
    for (int s4 = 0; s4 < 8; ++s4) {
      float4 wv[5], xv[4];
      #pragma unroll
      for (int i = 0; i < 5; ++i) {
        int v = vg*5 + i;
        wv[i] = *(const float4*)(wb + v*32 + ((s4 ^ (v & 7)) << 2));
      }
      #pragma unroll
      for (int j = 0; j < 4; ++j) {
        int b = bg*4 + j;
        xv[j] = *(const float4*)(xp + b*32 + ((s4 ^ (b >> 2)) << 2));
      }
      #pragma unroll
      for (int i = 0; i < 5; ++i)
        #pragma unroll
        for (int j = 0; j < 4; ++j)
          acc[i][j] += wv[i].x*xv[j].x + wv[i].y*xv[j].y + wv[i].z*xv[j].z + wv[i].w*xv[j].w;
    }
    if (pp < 6 && p + 2 < 1287) {
      asm volatile("s_waitcnt lgkmcnt(0)" ::: "memory");
      #pragma unroll
      for (int i = 0; i < 5; ++i) {
        int g = i*64 + lane, v = g >> 3, s4 = (g & 7) ^ (v & 7);
        gload16(Wl + (size_t)(p+2)*1280 + (v*8 + s4)*4, myw + cur*1280 + i*256);
      }
    }
    float* up = u + ((size_t)(bg*1287 + p))*6400 + l*160;
    #pragma unroll
    for (int i = 0; i < 5; ++i) {
      int v = vg*5 + i;
      *(float4*)(up + v*4) = make_float4(acc[i][0], acc[i][1], acc[i][2], acc[i][3]);
      #pragma unroll
      for (int j = 0; j < 4; ++j) s0acc[i][j] += acc[i][j];
    }
    cur ^= 1;
  }
  float* sp = s0part + (size_t)chunk*51200 + l*1280;
  #pragma unroll
  for (int i = 0; i < 5; ++i) {
    int v = vg*5 + i;
    *(float4*)(sp + v*32 + bg*4) =
        make_float4(s0acc[i][0], s0acc[i][1], s0acc[i][2], s0acc[i][3]);
  }
}

// ---------------------------------------------------------------------------
// squash kernels (unchanged, validated)
// ---------------------------------------------------------------------------
__global__ __launch_bounds__(64) void k_squash0(
    const float* __restrict__ s0, float* __restrict__ v0t)
{
  const int b = blockIdx.x / 40, l = blockIdx.x % 40, t = threadIdx.x;
  float s = 0.f;
  if (t < 40) s = s0[(l*40 + t)*32 + b] * (1.f/40.f);
  float sq = s*s;
  #pragma unroll
  for (int d = 1; d < 64; d <<= 1) sq += __shfl_xor(sq, d);
  float scale = sq > 0.f ? sq / ((1.f + sq) * sqrtf(sq)) : 0.f;
  if (t < 40) v0t[((size_t)(b >> 2)*1600 + l*40 + t)*4 + (b & 3)] = s * scale;
}

__global__ __launch_bounds__(64) void k_squash1(
    const float* __restrict__ sred, float* __restrict__ v1t)
{
  const int b = blockIdx.x / 40, l = blockIdx.x % 40, t = threadIdx.x;
  float s = 0.f;
  size_t off = ((size_t)(b >> 2)*1600 + l*40 + t)*4 + (b & 3);
  if (t < 40) s = sred[off];
  float sq = s*s;
  #pragma unroll
  for (int d = 1; d < 64; d <<= 1) sq += __shfl_xor(sq, d);
  float scale = sq > 0.f ? sq / ((1.f + sq) * sqrtf(sq)) : 0.f;
  if (t < 40) v1t[off] = s * scale;
}

__global__ __launch_bounds__(64) void k_final(
    const float* __restrict__ sred, float* __restrict__ out)
{
  const int b = blockIdx.x / 40, l = blockIdx.x % 40, t = threadIdx.x;
  float s = 0.f;
  if (t < 40) s = sred[((size_t)(b >> 2)*1600 + l*40 + t)*4 + (b & 3)];
  float sq = s*s, ss = s;
  #pragma unroll
  for (int d = 1; d < 64; d <<= 1) { sq += __shfl_xor(sq, d); ss += __shfl_xor(ss, d); }
  float scale = sq > 0.f ? sq / ((1.f + sq) * sqrtf(sq)) : 0.f;
  if (t == 0) out[b*40 + l] = ss * scale;
}

// ---------------------------------------------------------------------------
// k_route5: route4 + DEPTH-2 prefetch (the single change this round).
// Triple-buffered uu[3][4]; loads for p+2 issue in phase A of p -> two full
// iterations (A..D + A..D) of hiding before consumption. Loop fully unrolled
// so all buffer indices are compile-time constants (no scratch).
// ---------------------------------------------------------------------------
#define RPC 13
#define NCHUNK 99               // 99*13 = 1287 exactly
__global__ __launch_bounds__(400) void k_route5(
    const float* __restrict__ u, const float* __restrict__ vprev,
    float* __restrict__ b1g, float* __restrict__ spart, int pass)
{
  __shared__ float4 dred[400];
  __shared__ float dot_lds[160];   // [b4][40]
  __shared__ float c_lds[160];     // [b4][40]
  const int q4 = blockIdx.x & 7, chunk = blockIdx.x >> 3;
  const int t = threadIdx.x;            // t = l*10 + vq
  const int l = t / 10;
  const int p0 = chunk * RPC;
  const float4* u4 = (const float4*)u;
  const float4* vp4 = (const float4*)vprev + (size_t)q4*1600;

  float4 vv[4], s4[4], uu[3][4];
  float bprev[3] = {0.f, 0.f, 0.f};
  #pragma unroll
  for (int j = 0; j < 4; ++j) {
    vv[j] = vp4[t*4 + j];
    s4[j] = make_float4(0.f, 0.f, 0.f, 0.f);
  }
  // prologue: p0 -> buf0, p0+1 -> buf1
  {
    const float4* up0 = u4 + ((size_t)q4*1287 + p0)*1600;
    const float4* up1 = u4 + ((size_t)q4*1287 + p0 + 1)*1600;
    #pragma unroll
    for (int j = 0; j < 4; ++j) { uu[0][j] = up0[t*4 + j]; uu[1][j] = up1[t*4 + j]; }
    if (pass == 2 && t < 160) {
      bprev[0] = b1g[((size_t)q4*1287 + p0)*160 + t];
      bprev[1] = b1g[((size_t)q4*1287 + p0 + 1)*160 + t];
    }
  }

  #pragma unroll
  for (int pl = 0; pl < RPC; ++pl) {
    const int cur = pl % 3, pf = (pl + 2) % 3;
    const size_t qp = (size_t)q4*1287 + p0 + pl;
    // ---- A: dot partial from uu[cur]; issue depth-2 prefetch into uu[pf]
    float4 dp = make_float4(0.f, 0.f, 0.f, 0.f);
    #pragma unroll
    for (int j = 0; j < 4; ++j) {
      dp.x += uu[cur][j].x*vv[j].x; dp.y += uu[cur][j].y*vv[j].y;
      dp.z += uu[cur][j].z*vv[j].z; dp.w += uu[cur][j].w*vv[j].w;
    }
    dred[t] = dp;
    if (pl + 2 < RPC) {
      const float4* upn = u4 + (qp + 2)*1600;
      #pragma unroll
      for (int j = 0; j < 4; ++j) uu[pf][j] = upn[t*4 + j];
      if (pass == 2 && t < 160) bprev[pf] = b1g[(qp + 2)*160 + t];
    }
    barrier_nodrain();
    // ---- B: reduce -> dot_lds[b4][40], b1g io
    if (t < 160) {
      const int lr = t >> 2, b4 = t & 3;
      float d = 0.f;
      #pragma unroll
      for (int vq = 0; vq < 10; ++vq)
        d += ((const float*)&dred[lr*10 + vq])[b4];
      if (pass == 2) d += bprev[cur];
      else           b1g[qp*160 + t] = d;
      dot_lds[b4*40 + lr] = d;
    }
    barrier_nodrain();
    // ---- C: wave-parallel softmax (wave = b4, lane = l)
    if (t < 256) {
      const int b4 = t >> 6, ll = t & 63;
      float d = (ll < 40) ? dot_lds[b4*40 + ll] : -1e30f;
      float m = d;
      #pragma unroll
      for (int off = 32; off; off >>= 1) m = fmaxf(m, __shfl_xor(m, off));
      float e = expf(d - m);
      float Z = e;
      #pragma unroll
      for (int off = 32; off; off >>= 1) Z += __shfl_xor(Z, off);
      if (ll < 40) c_lds[b4*40 + ll] = e * (1.f / Z);
    }
    barrier_nodrain();
    // ---- D: s accumulate from registers
    {
      float c0 = c_lds[l], c1 = c_lds[40 + l], c2 = c_lds[80 + l], c3 = c_lds[120 + l];
      #pragma unroll
      for (int j = 0; j < 4; ++j) {
        s4[j].x += uu[cur][j].x*c0; s4[j].y += uu[cur][j].y*c1;
        s4[j].z += uu[cur][j].z*c2; s4[j].w += uu[cur][j].w*c3;
      }
    }
  }
  float4* sp = (float4*)(spart + ((size_t)chunk*8 + q4)*6400);
  #pragma unroll
  for (int j = 0; j < 4; ++j) sp[t*4 + j] = s4[j];
}

// sout[w] = sum_{c<n} src[c][w], w < 51200
__global__ __launch_bounds__(256) void k_reduceN(
    const float* __restrict__ src, float* __restrict__ sout, int n)
{
  const int w = blockIdx.x*256 + threadIdx.x;
  float s = 0.f;
  #pragma unroll 4
  for (int c = 0; c < n; ++c) s += src[(size_t)c*51200 + w];
  sout[w] = s;
}

// ---------------------------------------------------------------------------
extern "C" void kernel_launch(void* const* d_in, const int* in_sizes, int n_in,
                              void* d_out, int out_size, void* d_ws, size_t ws_size,
                              hipStream_t stream)
{
  const float* data = (const float*)d_in[0];
  const float* w1   = (const float*)d_in[1];
  const float* w2   = (const float*)d_in[2];
  const float* w3   = (const float*)d_in[3];
  const float* lw   = (const float*)d_in[4];
  const float* bg   = (const float*)d_in[5];
  const float* bb   = (const float*)d_in[6];
  const float* bm   = (const float*)d_in[7];
  const float* bv   = (const float*)d_in[8];
  const float* W    = (const float*)d_in[9];
  float* out = (float*)d_out;

  float* u      = (float*)d_ws;            // 8*1287*6400 = 65,894,400
  float* s0     = u + 65894400;            // 51,200
  float* v0t    = s0 + 51200;              // 51,200
  float* v1t    = v0t + 51200;             // 51,200
  float* s1     = v1t + 51200;             // 51,200
  float* xt     = s1 + 51200;              // 1,317,888
  float* big    = xt + 1317888;
  float* s0part = big;                     // [161][51200] (dead after reduce)
  float* b1g    = big;                     // 1,647,360 (live pass1 -> pass2)
  float* spart  = b1g + 1647360;           // [99][51200] = 5,068,800
  // total ~303 MB

  const int KU_LDS = (8192 + 4*2*1280) * 4;  // 73,728 B
  hipFuncSetAttribute((const void*)k_uhat,
                      hipFuncAttributeMaxDynamicSharedMemorySize, KU_LDS);

  k_front<<<256, 256, 0, stream>>>(data, w1, w2, w3, lw, bg, bb, bm, bv, xt);
  k_uhat<<<1610, 256, KU_LDS, stream>>>(W, xt, u, s0part);
  k_reduceN<<<200, 256, 0, stream>>>(s0part, s0, 161);
  k_squash0<<<1280, 64, 0, stream>>>(s0, v0t);

  k_route5<<<NCHUNK*8, 400, 0, stream>>>(u, v0t, b1g, spart, 1);
  k_reduceN<<<200, 256, 0, stream>>>(spart, s1, NCHUNK);
  k_squash1<<<1280, 64, 0, stream>>>(s1, v1t);

  k_route5<<<NCHUNK*8, 400, 0, stream>>>(u, v1t, b1g, spart, 2);
  k_reduceN<<<200, 256, 0, stream>>>(spart, s0, NCHUNK);
  k_final<<<1280, 64, 0, stream>>>(s0, out);
}

// Round 13
// 440.593 us; speedup vs baseline: 1.0708x; 1.0310x over previous
//
#include <hip/hip_runtime.h>

#define EPSB 1e-5f
#define NEG 0.2f

__device__ __forceinline__ float lrelu(float y) { return y >= 0.f ? y : NEG * y; }

// async global->LDS 16B/lane (wave-uniform LDS dest, per-lane global src)
typedef const __attribute__((address_space(1))) unsigned int gas1_u32;
typedef __attribute__((address_space(3))) unsigned int as3_u32;
__device__ __forceinline__ void gload16(const float* g, float* l) {
  __builtin_amdgcn_global_load_lds((gas1_u32*)g, (as3_u32*)l, 16, 0, 0);
}
// NT variant: CPol NT bit (=2 on gfx94x/95x) -- W is read-once, keep it out
// of L2/L3 so u stays resident for the route passes.
__device__ __forceinline__ void gload16nt(const float* g, float* l) {
  __builtin_amdgcn_global_load_lds((gas1_u32*)g, (as3_u32*)l, 16, 0, 2);
}
#define WAITVM(N) asm volatile("s_waitcnt vmcnt(" #N ")" ::: "memory")

// clang native vector for nontemporal builtins (HIP float4 is a class type)
typedef float floatx4 __attribute__((ext_vector_type(4)));
__device__ __forceinline__ void nt_store4(float4 v, float* addr) {
  floatx4 w = {v.x, v.y, v.z, v.w};
  __builtin_nontemporal_store(w, (floatx4*)addr);
}

// barrier that does NOT drain vmcnt (keeps global prefetches in flight);
// lgkmcnt(0) gives LDS store/load visibility, s_barrier syncs the block.
__device__ __forceinline__ void barrier_nodrain() {
  asm volatile("s_waitcnt lgkmcnt(0)" ::: "memory");
  __builtin_amdgcn_s_barrier();
  __builtin_amdgcn_sched_barrier(0);
}

// ---------------------------------------------------------------------------
// Fused conv frontend (unchanged, validated): output xt[p][b][s].
// ---------------------------------------------------------------------------
__global__ __launch_bounds__(256) void k_front(
    const float* __restrict__ data, const float* __restrict__ w1,
    const float* __restrict__ w2, const float* __restrict__ w3,
    const float* __restrict__ lw, const float* __restrict__ bg,
    const float* __restrict__ bb, const float* __restrict__ bm,
    const float* __restrict__ bv, float* __restrict__ xt)
{
  __shared__ float x1s[32][132];
  __shared__ float x2s[32][40];
  __shared__ float x3s[32][20];
  const int b = blockIdx.x >> 3, q = blockIdx.x & 7, t = threadIdx.x;
  const int o1s = (937*q)/8, o1e = (937*(q+1))/8;
  const int o2s = (234*q)/8, o2e = (234*(q+1))/8;
  const int o3s = (116*q)/8, o3e = (116*(q+1))/8;
  int n2s = min(o2s, 2*o3s);
  int n2e = max(o2e, 2*(o3e-1)+4); if (n2e > 234) n2e = 234;
  int n1s = min(o1s, 4*n2s);
  int n1e = max(o1e, 4*(n2e-1)+5); if (n1e > 937) n1e = 937;
  const int w1w = n1e - n1s, w2w = n2e - n2s, w3w = o3e - o3s;

  for (int idx = t; idx < 32*w1w; idx += 256) {
    int c = idx / w1w, j = n1s + idx % w1w;
    float acc = 0.f;
    int base = 5*j - 2;
    #pragma unroll
    for (int k = 0; k < 5; ++k) {
      int pos = base + k;
      float d = (pos >= 0 && pos < 4681) ? data[b*4681 + pos] : 0.f;
      acc += w1[c*5 + k] * d;
    }
    float sc = bg[c] * rsqrtf(bv[c] + EPSB);
    x1s[c][j - n1s] = lrelu((acc - bm[c]) * sc + bb[c]);
  }
  __syncthreads();
  for (int idx = t; idx < 32*w2w; idx += 256) {
    int c = idx / w2w, j = n2s + idx % w2w;
    float acc = 0.f;
    int col = 4*j - n1s;
    for (int ci = 0; ci < 32; ++ci) {
      #pragma unroll
      for (int k = 0; k < 5; ++k) acc += w2[(c*32 + ci)*5 + k] * x1s[ci][col + k];
    }
    float sc = bg[32+c] * rsqrtf(bv[32+c] + EPSB);
    x2s[c][j - n2s] = lrelu((acc - bm[32+c]) * sc + bb[32+c]);
  }
  __syncthreads();
  for (int idx = t; idx < 32*w3w; idx += 256) {
    int c = idx / w3w, j = o3s + idx % w3w;
    float acc = 0.f;
    int col = 2*j - n2s;
    for (int ci = 0; ci < 32; ++ci) {
      #pragma unroll
      for (int k = 0; k < 4; ++k) acc += w3[(c*32 + ci)*4 + k] * x2s[ci][col + k];
    }
    float sc = bg[64+c] * rsqrtf(bv[64+c] + EPSB);
    x3s[c][j - o3s] = lrelu((acc - bm[64+c]) * sc + bb[64+c]);
  }
  __syncthreads();
  const int np1 = o1e - o1s, np2 = o2e - o2s, np3 = o3e - o3s;
  const int np = np1 + np2 + np3;
  for (int idx = t; idx < np*32; idx += 256) {
    int pi = idx >> 5, s = idx & 31;
    float acc = 0.f;
    int p;
    if (pi < np1) {
      int j = o1s + pi; p = j;
      int col = j - n1s;
      for (int ci = 0; ci < 32; ++ci) acc += lw[s*32 + ci] * x1s[ci][col];
    } else if (pi < np1 + np2) {
      int j = o2s + (pi - np1); p = 937 + j;
      int col = j - n2s;
      for (int ci = 0; ci < 32; ++ci) acc += lw[s*32 + ci] * x2s[ci][col];
    } else {
      int j = o3s + (pi - np1 - np2); p = 1171 + j;
      int col = j - o3s;
      for (int ci = 0; ci < 32; ++ci) acc += lw[s*32 + ci] * x3s[ci][col];
    }
    float sc = bg[96+s] * rsqrtf(bv[96+s] + EPSB);
    xt[p*1024 + b*32 + s] = lrelu((acc - bm[96+s]) * sc + bb[96+s]);
  }
}

// ---------------------------------------------------------------------------
// Pass A: R4 structure (best measured, 4x reproduced). Only change this
// round: W DMA uses the NT cache hint (read-once data; keep L3 for u), and
// the s0part epilogue uses nontemporal stores.
// ---------------------------------------------------------------------------
__global__ __launch_bounds__(256) void k_uhat(
    const float* __restrict__ W, const float* __restrict__ xt,
    float* __restrict__ u, float* __restrict__ s0part)
{
  extern __shared__ float lds[];
  float* xs = lds;                       // [8 p][32 b][32 s] swizzled
  float* wbuf = lds + 8192;              // [4 waves][2][1280]
  const int t = threadIdx.x;
  const int wi = blockIdx.x*4 + (t >> 6);
  const int lane = t & 63;
  const int l = wi % 40, chunk = wi / 40;
  const int vg = lane >> 3, bg = lane & 7;
  const int p0 = chunk * 8;
  float* myw = wbuf + (t >> 6) * 2560;
  const float* Wl = W + (size_t)l * 1287 * 1280;

  for (int g = t; g < 2048; g += 256) {
    int pl = g >> 8, rem = g & 255;
    int b = rem >> 3, s4 = rem & 7;
    int pg = p0 + pl;
    float4 v = make_float4(0.f, 0.f, 0.f, 0.f);
    if (pg < 1287) v = *(const float4*)(xt + pg*1024 + b*32 + s4*4);
    *(float4*)(xs + pl*1024 + b*32 + ((s4 ^ (b >> 2)) << 2)) = v;
  }
  {
    #pragma unroll
    for (int i = 0; i < 5; ++i) {
      int g = i*64 + lane, v = g >> 3, s4 = (g & 7) ^ (v & 7);
      gload16nt(Wl + (size_t)p0*1280 + (v*8 + s4)*4, myw + i*256);
    }
    if (p0 + 1 < 1287) {
      #pragma unroll
      for (int i = 0; i < 5; ++i) {
        int g = i*64 + lane, v = g >> 3, s4 = (g & 7) ^ (v & 7);
        gload16nt(Wl + (size_t)(p0+1)*1280 + (v*8 + s4)*4, myw + 1280 + i*256);
      }
    }
  }
  __syncthreads();

  float s0acc[5][4] = {};
  int cur = 0;
  for (int pp = 0; pp < 8; ++pp) {
    int p = p0 + pp;
    if (p >= 1287) break;
    asm volatile("s_waitcnt lgkmcnt(0)" ::: "memory");
    WAITVM(5);
    const float* wb = myw + cur*1280;
    const float* xp = xs + pp*1024;
    float acc[5][4] = {};
    #pragma unroll
    for (int s4 = 0; s4 < 8; ++s4) {
      float4 wv[5], xv[4];
      #pragma unroll
      for (int i = 0; i < 5; ++i) {
        int v = vg*5 + i;
        wv[i] = *(const float4*)(wb + v*32 + ((s4 ^ (v & 7)) << 2));
      }
      #pragma unroll
      for (int j = 0; j < 4; ++j) {
        int b = bg*4 + j;
        xv[j] = *(const float4*)(xp + b*32 + ((s4 ^ (b >> 2)) << 2));
      }
      #pragma unroll
      for (int i = 0; i < 5; ++i)
        #pragma unroll
        for (int j = 0; j < 4; ++j)
          acc[i][j] += wv[i].x*xv[j].x + wv[i].y*xv[j].y + wv[i].z*xv[j].z + wv[i].w*xv[j].w;
    }
    if (pp < 6 && p + 2 < 1287) {
      asm volatile("s_waitcnt lgkmcnt(0)" ::: "memory");
      #pragma unroll
      for (int i = 0; i < 5; ++i) {
        int g = i*64 + lane, v = g >> 3, s4 = (g & 7) ^ (v & 7);
        gload16nt(Wl + (size_t)(p+2)*1280 + (v*8 + s4)*4, myw + cur*1280 + i*256);
      }
    }
    float* up = u + ((size_t)(bg*1287 + p))*6400 + l*160;
    #pragma unroll
    for (int i = 0; i < 5; ++i) {
      int v = vg*5 + i;
      *(float4*)(up + v*4) = make_float4(acc[i][0], acc[i][1], acc[i][2], acc[i][3]);
      #pragma unroll
      for (int j = 0; j < 4; ++j) s0acc[i][j] += acc[i][j];
    }
    cur ^= 1;
  }
  float* sp = s0part + (size_t)chunk*51200 + l*1280;
  #pragma unroll
  for (int i = 0; i < 5; ++i) {
    int v = vg*5 + i;
    nt_store4(make_float4(s0acc[i][0], s0acc[i][1], s0acc[i][2], s0acc[i][3]),
              sp + v*32 + bg*4);
  }
}

// ---------------------------------------------------------------------------
// squash kernels (unchanged, validated)
// ---------------------------------------------------------------------------
__global__ __launch_bounds__(64) void k_squash0(
    const float* __restrict__ s0, float* __restrict__ v0t)
{
  const int b = blockIdx.x / 40, l = blockIdx.x % 40, t = threadIdx.x;
  float s = 0.f;
  if (t < 40) s = s0[(l*40 + t)*32 + b] * (1.f/40.f);
  float sq = s*s;
  #pragma unroll
  for (int d = 1; d < 64; d <<= 1) sq += __shfl_xor(sq, d);
  float scale = sq > 0.f ? sq / ((1.f + sq) * sqrtf(sq)) : 0.f;
  if (t < 40) v0t[((size_t)(b >> 2)*1600 + l*40 + t)*4 + (b & 3)] = s * scale;
}

__global__ __launch_bounds__(64) void k_squash1(
    const float* __restrict__ sred, float* __restrict__ v1t)
{
  const int b = blockIdx.x / 40, l = blockIdx.x % 40, t = threadIdx.x;
  float s = 0.f;
  size_t off = ((size_t)(b >> 2)*1600 + l*40 + t)*4 + (b & 3);
  if (t < 40) s = sred[off];
  float sq = s*s;
  #pragma unroll
  for (int d = 1; d < 64; d <<= 1) sq += __shfl_xor(sq, d);
  float scale = sq > 0.f ? sq / ((1.f + sq) * sqrtf(sq)) : 0.f;
  if (t < 40) v1t[off] = s * scale;
}

__global__ __launch_bounds__(64) void k_final(
    const float* __restrict__ sred, float* __restrict__ out)
{
  const int b = blockIdx.x / 40, l = blockIdx.x % 40, t = threadIdx.x;
  float s = 0.f;
  if (t < 40) s = sred[((size_t)(b >> 2)*1600 + l*40 + t)*4 + (b & 3)];
  float sq = s*s, ss = s;
  #pragma unroll
  for (int d = 1; d < 64; d <<= 1) { sq += __shfl_xor(sq, d); ss += __shfl_xor(ss, d); }
  float scale = sq > 0.f ? sq / ((1.f + sq) * sqrtf(sq)) : 0.f;
  if (t == 0) out[b*40 + l] = ss * scale;
}

// ---------------------------------------------------------------------------
// k_route5 (R11 structure) + L3-aware chunk ordering: pass 1 walks chunks in
// REVERSE p-order (read newest-written u first: MRU-first avoids cyclic-LRU
// thrash of the 263MB-vs-256MB working set); pass 2 walks forward (= reverse
// of pass 1's touch order). spart stores are nontemporal (read-once).
// ---------------------------------------------------------------------------
#define RPC 13
#define NCHUNK 99               // 99*13 = 1287 exactly
__global__ __launch_bounds__(400) void k_route5(
    const float* __restrict__ u, const float* __restrict__ vprev,
    float* __restrict__ b1g, float* __restrict__ spart, int pass)
{
  __shared__ float4 dred[400];
  __shared__ float dot_lds[160];   // [b4][40]
  __shared__ float c_lds[160];     // [b4][40]
  const int q4 = blockIdx.x & 7;
  const int chunk0 = blockIdx.x >> 3;
  const int chunk = (pass == 1) ? (NCHUNK - 1 - chunk0) : chunk0;
  const int t = threadIdx.x;            // t = l*10 + vq
  const int l = t / 10;
  const int p0 = chunk * RPC;
  const float4* u4 = (const float4*)u;
  const float4* vp4 = (const float4*)vprev + (size_t)q4*1600;

  float4 vv[4], s4[4], uu[3][4];
  float bprev[3] = {0.f, 0.f, 0.f};
  #pragma unroll
  for (int j = 0; j < 4; ++j) {
    vv[j] = vp4[t*4 + j];
    s4[j] = make_float4(0.f, 0.f, 0.f, 0.f);
  }
  // prologue: p0 -> buf0, p0+1 -> buf1
  {
    const float4* up0 = u4 + ((size_t)q4*1287 + p0)*1600;
    const float4* up1 = u4 + ((size_t)q4*1287 + p0 + 1)*1600;
    #pragma unroll
    for (int j = 0; j < 4; ++j) { uu[0][j] = up0[t*4 + j]; uu[1][j] = up1[t*4 + j]; }
    if (pass == 2 && t < 160) {
      bprev[0] = b1g[((size_t)q4*1287 + p0)*160 + t];
      bprev[1] = b1g[((size_t)q4*1287 + p0 + 1)*160 + t];
    }
  }

  #pragma unroll
  for (int pl = 0; pl < RPC; ++pl) {
    const int cur = pl % 3, pf = (pl + 2) % 3;
    const size_t qp = (size_t)q4*1287 + p0 + pl;
    // ---- A: dot partial from uu[cur]; issue depth-2 prefetch into uu[pf]
    float4 dp = make_float4(0.f, 0.f, 0.f, 0.f);
    #pragma unroll
    for (int j = 0; j < 4; ++j) {
      dp.x += uu[cur][j].x*vv[j].x; dp.y += uu[cur][j].y*vv[j].y;
      dp.z += uu[cur][j].z*vv[j].z; dp.w += uu[cur][j].w*vv[j].w;
    }
    dred[t] = dp;
    if (pl + 2 < RPC) {
      const float4* upn = u4 + (qp + 2)*1600;
      #pragma unroll
      for (int j = 0; j < 4; ++j) uu[pf][j] = upn[t*4 + j];
      if (pass == 2 && t < 160) bprev[pf] = b1g[(qp + 2)*160 + t];
    }
    barrier_nodrain();
    // ---- B: reduce -> dot_lds[b4][40], b1g io
    if (t < 160) {
      const int lr = t >> 2, b4 = t & 3;
      float d = 0.f;
      #pragma unroll
      for (int vq = 0; vq < 10; ++vq)
        d += ((const float*)&dred[lr*10 + vq])[b4];
      if (pass == 2) d += bprev[cur];
      else           b1g[qp*160 + t] = d;
      dot_lds[b4*40 + lr] = d;
    }
    barrier_nodrain();
    // ---- C: wave-parallel softmax (wave = b4, lane = l)
    if (t < 256) {
      const int b4 = t >> 6, ll = t & 63;
      float d = (ll < 40) ? dot_lds[b4*40 + ll] : -1e30f;
      float m = d;
      #pragma unroll
      for (int off = 32; off; off >>= 1) m = fmaxf(m, __shfl_xor(m, off));
      float e = expf(d - m);
      float Z = e;
      #pragma unroll
      for (int off = 32; off; off >>= 1) Z += __shfl_xor(Z, off);
      if (ll < 40) c_lds[b4*40 + ll] = e * (1.f / Z);
    }
    barrier_nodrain();
    // ---- D: s accumulate from registers
    {
      float c0 = c_lds[l], c1 = c_lds[40 + l], c2 = c_lds[80 + l], c3 = c_lds[120 + l];
      #pragma unroll
      for (int j = 0; j < 4; ++j) {
        s4[j].x += uu[cur][j].x*c0; s4[j].y += uu[cur][j].y*c1;
        s4[j].z += uu[cur][j].z*c2; s4[j].w += uu[cur][j].w*c3;
      }
    }
  }
  float* sp = spart + ((size_t)chunk*8 + q4)*6400;
  #pragma unroll
  for (int j = 0; j < 4; ++j)
    nt_store4(s4[j], sp + (t*4 + j)*4);
}

// sout[w] = sum_{c<n} src[c][w], w < 51200  (read-once source: NT loads)
__global__ __launch_bounds__(256) void k_reduceN(
    const float* __restrict__ src, float* __restrict__ sout, int n)
{
  const int w = blockIdx.x*256 + threadIdx.x;
  float s = 0.f;
  #pragma unroll 4
  for (int c = 0; c < n; ++c)
    s += __builtin_nontemporal_load(src + (size_t)c*51200 + w);
  sout[w] = s;
}

// ---------------------------------------------------------------------------
extern "C" void kernel_launch(void* const* d_in, const int* in_sizes, int n_in,
                              void* d_out, int out_size, void* d_ws, size_t ws_size,
                              hipStream_t stream)
{
  const float* data = (const float*)d_in[0];
  const float* w1   = (const float*)d_in[1];
  const float* w2   = (const float*)d_in[2];
  const float* w3   = (const float*)d_in[3];
  const float* lw   = (const float*)d_in[4];
  const float* bg   = (const float*)d_in[5];
  const float* bb   = (const float*)d_in[6];
  const float* bm   = (const float*)d_in[7];
  const float* bv   = (const float*)d_in[8];
  const float* W    = (const float*)d_in[9];
  float* out = (float*)d_out;

  float* u      = (float*)d_ws;            // 8*1287*6400 = 65,894,400
  float* s0     = u + 65894400;            // 51,200
  float* v0t    = s0 + 51200;              // 51,200
  float* v1t    = v0t + 51200;             // 51,200
  float* s1     = v1t + 51200;             // 51,200
  float* xt     = s1 + 51200;              // 1,317,888
  float* big    = xt + 1317888;
  float* s0part = big;                     // [161][51200] (dead after reduce)
  float* b1g    = big;                     // 1,647,360 (live pass1 -> pass2)
  float* spart  = b1g + 1647360;           // [99][51200] = 5,068,800
  // total ~303 MB

  const int KU_LDS = (8192 + 4*2*1280) * 4;  // 73,728 B
  hipFuncSetAttribute((const void*)k_uhat,
                      hipFuncAttributeMaxDynamicSharedMemorySize, KU_LDS);

  k_front<<<256, 256, 0, stream>>>(data, w1, w2, w3, lw, bg, bb, bm, bv, xt);
  k_uhat<<<1610, 256, KU_LDS, stream>>>(W, xt, u, s0part);
  k_reduceN<<<200, 256, 0, stream>>>(s0part, s0, 161);
  k_squash0<<<1280, 64, 0, stream>>>(s0, v0t);

  k_route5<<<NCHUNK*8, 400, 0, stream>>>(u, v0t, b1g, spart, 1);
  k_reduceN<<<200, 256, 0, stream>>>(spart, s1, NCHUNK);
  k_squash1<<<1280, 64, 0, stream>>>(s1, v1t);

  k_route5<<<NCHUNK*8, 400, 0, stream>>>(u, v1t, b1g, spart, 2);
  k_reduceN<<<200, 256, 0, stream>>>(spart, s0, NCHUNK);
  k_final<<<1280, 64, 0, stream>>>(s0, out);
}

// Round 14
// 376.568 us; speedup vs baseline: 1.2529x; 1.1700x over previous
//
#include <hip/hip_runtime.h>

#define EPSB 1e-5f
#define NEG 0.2f

__device__ __forceinline__ float lrelu(float y) { return y >= 0.f ? y : NEG * y; }

// async global->LDS 16B/lane (wave-uniform LDS dest, per-lane global src)
typedef const __attribute__((address_space(1))) unsigned int gas1_u32;
typedef __attribute__((address_space(3))) unsigned int as3_u32;
__device__ __forceinline__ void gload16nt(const float* g, float* l) {
  __builtin_amdgcn_global_load_lds((gas1_u32*)g, (as3_u32*)l, 16, 0, 2);
}
#define WAITVM(N) asm volatile("s_waitcnt vmcnt(" #N ")" ::: "memory")

// clang native vectors
typedef float floatx4 __attribute__((ext_vector_type(4)));
typedef short bf16x8 __attribute__((ext_vector_type(8)));
__device__ __forceinline__ void nt_store4(float4 v, float* addr) {
  floatx4 w = {v.x, v.y, v.z, v.w};
  __builtin_nontemporal_store(w, (floatx4*)addr);
}

// barrier that does NOT drain vmcnt
__device__ __forceinline__ void barrier_nodrain() {
  asm volatile("s_waitcnt lgkmcnt(0)" ::: "memory");
  __builtin_amdgcn_s_barrier();
  __builtin_amdgcn_sched_barrier(0);
}

// ---------------------------------------------------------------------------
// Fused conv frontend (unchanged, validated): output xt[p][b][s].
// ---------------------------------------------------------------------------
__global__ __launch_bounds__(256) void k_front(
    const float* __restrict__ data, const float* __restrict__ w1,
    const float* __restrict__ w2, const float* __restrict__ w3,
    const float* __restrict__ lw, const float* __restrict__ bg,
    const float* __restrict__ bb, const float* __restrict__ bm,
    const float* __restrict__ bv, float* __restrict__ xt)
{
  __shared__ float x1s[32][132];
  __shared__ float x2s[32][40];
  __shared__ float x3s[32][20];
  const int b = blockIdx.x >> 3, q = blockIdx.x & 7, t = threadIdx.x;
  const int o1s = (937*q)/8, o1e = (937*(q+1))/8;
  const int o2s = (234*q)/8, o2e = (234*(q+1))/8;
  const int o3s = (116*q)/8, o3e = (116*(q+1))/8;
  int n2s = min(o2s, 2*o3s);
  int n2e = max(o2e, 2*(o3e-1)+4); if (n2e > 234) n2e = 234;
  int n1s = min(o1s, 4*n2s);
  int n1e = max(o1e, 4*(n2e-1)+5); if (n1e > 937) n1e = 937;
  const int w1w = n1e - n1s, w2w = n2e - n2s, w3w = o3e - o3s;

  for (int idx = t; idx < 32*w1w; idx += 256) {
    int c = idx / w1w, j = n1s + idx % w1w;
    float acc = 0.f;
    int base = 5*j - 2;
    #pragma unroll
    for (int k = 0; k < 5; ++k) {
      int pos = base + k;
      float d = (pos >= 0 && pos < 4681) ? data[b*4681 + pos] : 0.f;
      acc += w1[c*5 + k] * d;
    }
    float sc = bg[c] * rsqrtf(bv[c] + EPSB);
    x1s[c][j - n1s] = lrelu((acc - bm[c]) * sc + bb[c]);
  }
  __syncthreads();
  for (int idx = t; idx < 32*w2w; idx += 256) {
    int c = idx / w2w, j = n2s + idx % w2w;
    float acc = 0.f;
    int col = 4*j - n1s;
    for (int ci = 0; ci < 32; ++ci) {
      #pragma unroll
      for (int k = 0; k < 5; ++k) acc += w2[(c*32 + ci)*5 + k] * x1s[ci][col + k];
    }
    float sc = bg[32+c] * rsqrtf(bv[32+c] + EPSB);
    x2s[c][j - n2s] = lrelu((acc - bm[32+c]) * sc + bb[32+c]);
  }
  __syncthreads();
  for (int idx = t; idx < 32*w3w; idx += 256) {
    int c = idx / w3w, j = o3s + idx % w3w;
    float acc = 0.f;
    int col = 2*j - n2s;
    for (int ci = 0; ci < 32; ++ci) {
      #pragma unroll
      for (int k = 0; k < 4; ++k) acc += w3[(c*32 + ci)*4 + k] * x2s[ci][col + k];
    }
    float sc = bg[64+c] * rsqrtf(bv[64+c] + EPSB);
    x3s[c][j - o3s] = lrelu((acc - bm[64+c]) * sc + bb[64+c]);
  }
  __syncthreads();
  const int np1 = o1e - o1s, np2 = o2e - o2s, np3 = o3e - o3s;
  const int np = np1 + np2 + np3;
  for (int idx = t; idx < np*32; idx += 256) {
    int pi = idx >> 5, s = idx & 31;
    float acc = 0.f;
    int p;
    if (pi < np1) {
      int j = o1s + pi; p = j;
      int col = j - n1s;
      for (int ci = 0; ci < 32; ++ci) acc += lw[s*32 + ci] * x1s[ci][col];
    } else if (pi < np1 + np2) {
      int j = o2s + (pi - np1); p = 937 + j;
      int col = j - n2s;
      for (int ci = 0; ci < 32; ++ci) acc += lw[s*32 + ci] * x2s[ci][col];
    } else {
      int j = o3s + (pi - np1 - np2); p = 1171 + j;
      int col = j - o3s;
      for (int ci = 0; ci < 32; ++ci) acc += lw[s*32 + ci] * x3s[ci][col];
    }
    float sc = bg[96+s] * rsqrtf(bv[96+s] + EPSB);
    xt[p*1024 + b*32 + s] = lrelu((acc - bm[96+s]) * sc + bb[96+s]);
  }
}

// ---------------------------------------------------------------------------
// Pass A v6 (MFMA split-bf16): u = W·x via 3-term bf16 MFMA
//   (hi·hi + hi·lo + lo·hi; truncation split, rel err ~2^-17).
// D = A·B: A = x (M=b,2 tiles of 16), B = W (N=v, 3 tiles, pad 48), K=s=32.
// K-mapping is contraction-invariant (same lane->k bijection for A and B:
// slot j of lane-group g = s = g*8+j). C/D mapping (HW-verified m89):
// col=lane&15 -> v, row=(lane>>4)*4+reg -> b: lane's 4 regs = one aligned
// b-quad at fixed v -> writes match the existing u[q4][p][l][v][b4] layout.
// Outer structure = R4's (validated): block 4 waves, wave=(l,chunk of 8 p),
// W DMA double-buffered (NT), x staged per block (now as hi/lo bf16).
// Counted waits (6 stores+5 DMA per iter, unconditional clamped prefetch):
//   pp0: none(drained); pp1: 11; pp2-6: 17; pp7: 12.
// ---------------------------------------------------------------------------
__global__ __launch_bounds__(256) void k_uhat(
    const float* __restrict__ W, const float* __restrict__ xt,
    float* __restrict__ u, float* __restrict__ s0part)
{
  extern __shared__ float lds[];
  float* wbuf = lds;                                       // [4][2][1280] f32
  unsigned short* xs_hi = (unsigned short*)(lds + 10240);  // [8p][32b][40]
  unsigned short* xs_lo = xs_hi + 10240;                   // [8p][32b][40]
  const int t = threadIdx.x;
  const int wv = t >> 6, lane = t & 63;
  const int wi = blockIdx.x*4 + wv;
  const int l = wi % 40, chunk = wi / 40;
  const int p0 = chunk * 8;
  float* myw = wbuf + wv * 2560;
  const float* Wl = W + (size_t)l * 1287 * 1280;
  const int row = lane & 15, g = lane >> 4;

  // stage x: fp32 -> (hi,lo) truncated bf16; row stride 40 shorts (80B,
  // 2-way-bank-free); zeros for p >= 1287
  for (int idx = t; idx < 2048; idx += 256) {
    int pl = idx >> 8, rem = idx & 255;
    int b = rem >> 3, s4 = rem & 7;
    int pg = p0 + pl;
    float4 v = make_float4(0.f, 0.f, 0.f, 0.f);
    if (pg < 1287) v = *(const float4*)(xt + pg*1024 + b*32 + s4*4);
    unsigned int b0 = __float_as_uint(v.x), b1 = __float_as_uint(v.y);
    unsigned int b2 = __float_as_uint(v.z), b3 = __float_as_uint(v.w);
    ushort4 h, lo;
    h.x = (unsigned short)(b0 >> 16); h.y = (unsigned short)(b1 >> 16);
    h.z = (unsigned short)(b2 >> 16); h.w = (unsigned short)(b3 >> 16);
    lo.x = (unsigned short)(__float_as_uint(v.x - __uint_as_float(b0 & 0xffff0000u)) >> 16);
    lo.y = (unsigned short)(__float_as_uint(v.y - __uint_as_float(b1 & 0xffff0000u)) >> 16);
    lo.z = (unsigned short)(__float_as_uint(v.z - __uint_as_float(b2 & 0xffff0000u)) >> 16);
    lo.w = (unsigned short)(__float_as_uint(v.w - __uint_as_float(b3 & 0xffff0000u)) >> 16);
    int off = pl*1280 + b*40 + s4*4;
    *(ushort4*)(xs_hi + off) = h;
    *(ushort4*)(xs_lo + off) = lo;
  }
  // prologue W DMA (before barrier; drained by __syncthreads)
  #pragma unroll
  for (int i = 0; i < 5; ++i) {
    int gg = i*64 + lane, v = gg >> 3, s4 = (gg & 7) ^ (v & 7);
    gload16nt(Wl + (size_t)p0*1280 + (v*8 + s4)*4, myw + i*256);
  }
  #pragma unroll
  for (int i = 0; i < 5; ++i) {
    int gg = i*64 + lane, v = gg >> 3, s4 = (gg & 7) ^ (v & 7);
    gload16nt(Wl + (size_t)(p0+1)*1280 + (v*8 + s4)*4, myw + 1280 + i*256);
  }
  __syncthreads();

  floatx4 s0acc[2][3];
  #pragma unroll
  for (int mt = 0; mt < 2; ++mt)
    #pragma unroll
    for (int nt = 0; nt < 3; ++nt)
      s0acc[mt][nt] = (floatx4){0.f, 0.f, 0.f, 0.f};

  #pragma unroll
  for (int pp = 0; pp < 8; ++pp) {
    const int p = p0 + pp;
    if (p >= 1287) break;
    // counted waits (compile-time after unroll); see header comment
    if (pp == 1)      WAITVM(11);
    else if (pp >= 2 && pp <= 6) WAITVM(17);
    else if (pp == 7) WAITVM(12);
    const float* wb = myw + (pp & 1)*1280;
    // A-frags: x hi/lo, lane slot j = s = g*8+j
    const unsigned short* xh = xs_hi + pp*1280;
    const unsigned short* xl = xs_lo + pp*1280;
    bf16x8 aH[2], aL[2];
    aH[0] = *(const bf16x8*)(xh + row*40 + g*8);
    aH[1] = *(const bf16x8*)(xh + (16 + row)*40 + g*8);
    aL[0] = *(const bf16x8*)(xl + row*40 + g*8);
    aL[1] = *(const bf16x8*)(xl + (16 + row)*40 + g*8);
    floatx4 acc[2][3];
    #pragma unroll
    for (int mt = 0; mt < 2; ++mt)
      #pragma unroll
      for (int nt = 0; nt < 3; ++nt)
        acc[mt][nt] = (floatx4){0.f, 0.f, 0.f, 0.f};
    #pragma unroll
    for (int nt = 0; nt < 3; ++nt) {
      int vq = nt*16 + row;
      bool valid = vq < 40;
      int vv = valid ? vq : 0;
      // W[vv][s = g*8 .. g*8+7] from swizzled wbuf (two float4)
      float4 w0 = *(const float4*)(wb + vv*32 + (((2*g) ^ (vv & 7)) << 2));
      float4 w1 = *(const float4*)(wb + vv*32 + (((2*g + 1) ^ (vv & 7)) << 2));
      float ws[8] = {w0.x, w0.y, w0.z, w0.w, w1.x, w1.y, w1.z, w1.w};
      bf16x8 bH, bL;
      #pragma unroll
      for (int j = 0; j < 8; ++j) {
        unsigned int bits = __float_as_uint(ws[j]);
        unsigned short hs = (unsigned short)(bits >> 16);
        float lf = ws[j] - __uint_as_float(bits & 0xffff0000u);
        unsigned short lsv = (unsigned short)(__float_as_uint(lf) >> 16);
        bH[j] = valid ? (short)hs : (short)0;
        bL[j] = valid ? (short)lsv : (short)0;
      }
      #pragma unroll
      for (int mt = 0; mt < 2; ++mt) {
        acc[mt][nt] = __builtin_amdgcn_mfma_f32_16x16x32_bf16(aH[mt], bH, acc[mt][nt], 0, 0, 0);
        acc[mt][nt] = __builtin_amdgcn_mfma_f32_16x16x32_bf16(aH[mt], bL, acc[mt][nt], 0, 0, 0);
        acc[mt][nt] = __builtin_amdgcn_mfma_f32_16x16x32_bf16(aL[mt], bH, acc[mt][nt], 0, 0, 0);
      }
    }
    // prefetch D(p+2) into the just-consumed buffer (unconditional-clamped
    // so every chunk has identical vmcnt queue shape)
    if (pp < 6) {
      int psrc = p + 2; if (psrc > 1286) psrc = 1286;
      asm volatile("s_waitcnt lgkmcnt(0)" ::: "memory");
      __builtin_amdgcn_sched_barrier(0);
      #pragma unroll
      for (int i = 0; i < 5; ++i) {
        int gg = i*64 + lane, v = gg >> 3, s4 = (gg & 7) ^ (v & 7);
        gload16nt(Wl + (size_t)psrc*1280 + (v*8 + s4)*4, myw + (pp & 1)*1280 + i*256);
      }
    }
    // stores (6 per iter: lane's 4 regs = b-quad q4 at fixed v) + s0 acc
    #pragma unroll
    for (int mt = 0; mt < 2; ++mt)
      #pragma unroll
      for (int nt = 0; nt < 3; ++nt) {
        int vq = nt*16 + row;
        if (vq < 40) {
          int q4 = mt*4 + g;
          *(floatx4*)(u + ((size_t)(q4*1287 + p))*6400 + l*160 + vq*4) = acc[mt][nt];
          s0acc[mt][nt] += acc[mt][nt];
        }
      }
  }
  #pragma unroll
  for (int mt = 0; mt < 2; ++mt)
    #pragma unroll
    for (int nt = 0; nt < 3; ++nt) {
      int vq = nt*16 + row;
      if (vq < 40) {
        int q4 = mt*4 + g;
        *(floatx4*)(s0part + (size_t)chunk*51200 + l*1280 + vq*32 + q4*4) = s0acc[mt][nt];
      }
    }
}

// ---------------------------------------------------------------------------
// squash kernels (unchanged, validated)
// ---------------------------------------------------------------------------
__global__ __launch_bounds__(64) void k_squash0(
    const float* __restrict__ s0, float* __restrict__ v0t)
{
  const int b = blockIdx.x / 40, l = blockIdx.x % 40, t = threadIdx.x;
  float s = 0.f;
  if (t < 40) s = s0[(l*40 + t)*32 + b] * (1.f/40.f);
  float sq = s*s;
  #pragma unroll
  for (int d = 1; d < 64; d <<= 1) sq += __shfl_xor(sq, d);
  float scale = sq > 0.f ? sq / ((1.f + sq) * sqrtf(sq)) : 0.f;
  if (t < 40) v0t[((size_t)(b >> 2)*1600 + l*40 + t)*4 + (b & 3)] = s * scale;
}

__global__ __launch_bounds__(64) void k_squash1(
    const float* __restrict__ sred, float* __restrict__ v1t)
{
  const int b = blockIdx.x / 40, l = blockIdx.x % 40, t = threadIdx.x;
  float s = 0.f;
  size_t off = ((size_t)(b >> 2)*1600 + l*40 + t)*4 + (b & 3);
  if (t < 40) s = sred[off];
  float sq = s*s;
  #pragma unroll
  for (int d = 1; d < 64; d <<= 1) sq += __shfl_xor(sq, d);
  float scale = sq > 0.f ? sq / ((1.f + sq) * sqrtf(sq)) : 0.f;
  if (t < 40) v1t[off] = s * scale;
}

__global__ __launch_bounds__(64) void k_final(
    const float* __restrict__ sred, float* __restrict__ out)
{
  const int b = blockIdx.x / 40, l = blockIdx.x % 40, t = threadIdx.x;
  float s = 0.f;
  if (t < 40) s = sred[((size_t)(b >> 2)*1600 + l*40 + t)*4 + (b & 3)];
  float sq = s*s, ss = s;
  #pragma unroll
  for (int d = 1; d < 64; d <<= 1) { sq += __shfl_xor(sq, d); ss += __shfl_xor(ss, d); }
  float scale = sq > 0.f ? sq / ((1.f + sq) * sqrtf(sq)) : 0.f;
  if (t == 0) out[b*40 + l] = ss * scale;
}

// ---------------------------------------------------------------------------
// k_route5 (unchanged from R13, validated)
// ---------------------------------------------------------------------------
#define RPC 13
#define NCHUNK 99               // 99*13 = 1287 exactly
__global__ __launch_bounds__(400) void k_route5(
    const float* __restrict__ u, const float* __restrict__ vprev,
    float* __restrict__ b1g, float* __restrict__ spart, int pass)
{
  __shared__ float4 dred[400];
  __shared__ float dot_lds[160];   // [b4][40]
  __shared__ float c_lds[160];     // [b4][40]
  const int q4 = blockIdx.x & 7;
  const int chunk0 = blockIdx.x >> 3;
  const int chunk = (pass == 1) ? (NCHUNK - 1 - chunk0) : chunk0;
  const int t = threadIdx.x;            // t = l*10 + vq
  const int l = t / 10;
  const int p0 = chunk * RPC;
  const float4* u4 = (const float4*)u;
  const float4* vp4 = (const float4*)vprev + (size_t)q4*1600;

  float4 vv[4], s4[4], uu[3][4];
  float bprev[3] = {0.f, 0.f, 0.f};
  #pragma unroll
  for (int j = 0; j < 4; ++j) {
    vv[j] = vp4[t*4 + j];
    s4[j] = make_float4(0.f, 0.f, 0.f, 0.f);
  }
  {
    const float4* up0 = u4 + ((size_t)q4*1287 + p0)*1600;
    const float4* up1 = u4 + ((size_t)q4*1287 + p0 + 1)*1600;
    #pragma unroll
    for (int j = 0; j < 4; ++j) { uu[0][j] = up0[t*4 + j]; uu[1][j] = up1[t*4 + j]; }
    if (pass == 2 && t < 160) {
      bprev[0] = b1g[((size_t)q4*1287 + p0)*160 + t];
      bprev[1] = b1g[((size_t)q4*1287 + p0 + 1)*160 + t];
    }
  }

  #pragma unroll
  for (int pl = 0; pl < RPC; ++pl) {
    const int cur = pl % 3, pf = (pl + 2) % 3;
    const size_t qp = (size_t)q4*1287 + p0 + pl;
    float4 dp = make_float4(0.f, 0.f, 0.f, 0.f);
    #pragma unroll
    for (int j = 0; j < 4; ++j) {
      dp.x += uu[cur][j].x*vv[j].x; dp.y += uu[cur][j].y*vv[j].y;
      dp.z += uu[cur][j].z*vv[j].z; dp.w += uu[cur][j].w*vv[j].w;
    }
    dred[t] = dp;
    if (pl + 2 < RPC) {
      const float4* upn = u4 + (qp + 2)*1600;
      #pragma unroll
      for (int j = 0; j < 4; ++j) uu[pf][j] = upn[t*4 + j];
      if (pass == 2 && t < 160) bprev[pf] = b1g[(qp + 2)*160 + t];
    }
    barrier_nodrain();
    if (t < 160) {
      const int lr = t >> 2, b4 = t & 3;
      float d = 0.f;
      #pragma unroll
      for (int vq = 0; vq < 10; ++vq)
        d += ((const float*)&dred[lr*10 + vq])[b4];
      if (pass == 2) d += bprev[cur];
      else           b1g[qp*160 + t] = d;
      dot_lds[b4*40 + lr] = d;
    }
    barrier_nodrain();
    if (t < 256) {
      const int b4 = t >> 6, ll = t & 63;
      float d = (ll < 40) ? dot_lds[b4*40 + ll] : -1e30f;
      float m = d;
      #pragma unroll
      for (int off = 32; off; off >>= 1) m = fmaxf(m, __shfl_xor(m, off));
      float e = expf(d - m);
      float Z = e;
      #pragma unroll
      for (int off = 32; off; off >>= 1) Z += __shfl_xor(Z, off);
      if (ll < 40) c_lds[b4*40 + ll] = e * (1.f / Z);
    }
    barrier_nodrain();
    {
      float c0 = c_lds[l], c1 = c_lds[40 + l], c2 = c_lds[80 + l], c3 = c_lds[120 + l];
      #pragma unroll
      for (int j = 0; j < 4; ++j) {
        s4[j].x += uu[cur][j].x*c0; s4[j].y += uu[cur][j].y*c1;
        s4[j].z += uu[cur][j].z*c2; s4[j].w += uu[cur][j].w*c3;
      }
    }
  }
  float* sp = spart + ((size_t)chunk*8 + q4)*6400;
  #pragma unroll
  for (int j = 0; j < 4; ++j)
    nt_store4(s4[j], sp + (t*4 + j)*4);
}

// sout[w] = sum_{c<n} src[c][w], w < 51200  (read-once source: NT loads)
__global__ __launch_bounds__(256) void k_reduceN(
    const float* __restrict__ src, float* __restrict__ sout, int n)
{
  const int w = blockIdx.x*256 + threadIdx.x;
  float s = 0.f;
  #pragma unroll 4
  for (int c = 0; c < n; ++c)
    s += __builtin_nontemporal_load(src + (size_t)c*51200 + w);
  sout[w] = s;
}

// ---------------------------------------------------------------------------
extern "C" void kernel_launch(void* const* d_in, const int* in_sizes, int n_in,
                              void* d_out, int out_size, void* d_ws, size_t ws_size,
                              hipStream_t stream)
{
  const float* data = (const float*)d_in[0];
  const float* w1   = (const float*)d_in[1];
  const float* w2   = (const float*)d_in[2];
  const float* w3   = (const float*)d_in[3];
  const float* lw   = (const float*)d_in[4];
  const float* bg   = (const float*)d_in[5];
  const float* bb   = (const float*)d_in[6];
  const float* bm   = (const float*)d_in[7];
  const float* bv   = (const float*)d_in[8];
  const float* W    = (const float*)d_in[9];
  float* out = (float*)d_out;

  float* u      = (float*)d_ws;            // 8*1287*6400 = 65,894,400
  float* s0     = u + 65894400;            // 51,200
  float* v0t    = s0 + 51200;              // 51,200
  float* v1t    = v0t + 51200;             // 51,200
  float* s1     = v1t + 51200;             // 51,200
  float* xt     = s1 + 51200;              // 1,317,888
  float* big    = xt + 1317888;
  float* s0part = big;                     // [161][51200] (dead after reduce)
  float* b1g    = big;                     // 1,647,360 (live pass1 -> pass2)
  float* spart  = b1g + 1647360;           // [99][51200] = 5,068,800
  // total ~303 MB

  const int KU_LDS = 10240*4 + 2*10240*2;  // 40KB wbuf + 40KB xs = 81,920 B
  hipFuncSetAttribute((const void*)k_uhat,
                      hipFuncAttributeMaxDynamicSharedMemorySize, KU_LDS);

  k_front<<<256, 256, 0, stream>>>(data, w1, w2, w3, lw, bg, bb, bm, bv, xt);
  k_uhat<<<1610, 256, KU_LDS, stream>>>(W, xt, u, s0part);
  k_reduceN<<<200, 256, 0, stream>>>(s0part, s0, 161);
  k_squash0<<<1280, 64, 0, stream>>>(s0, v0t);

  k_route5<<<NCHUNK*8, 400, 0, stream>>>(u, v0t, b1g, spart, 1);
  k_reduceN<<<200, 256, 0, stream>>>(spart, s1, NCHUNK);
  k_squash1<<<1280, 64, 0, stream>>>(s1, v1t);

  k_route5<<<NCHUNK*8, 400, 0, stream>>>(u, v1t, b1g, spart, 2);
  k_reduceN<<<200, 256, 0, stream>>>(spart, s0, NCHUNK);
  k_final<<<1280, 64, 0, stream>>>(s0, out);
}